// Round 1
// baseline (247.165 us; speedup 1.0000x reference)
//
#include <hip/hip_runtime.h>

// 2-layer fused LSTM + linear head.  B=8192, T=128, D=32, H=64, gates=256.
// Per WG (256 thr = 4 waves): BT=16 batch rows, all 128 steps, both layers.
// Weights = MFMA A-operand in registers; activations = B-operand.
//   A-frag (16x16x32 f16): lane l supplies A[l&15][8*(l>>4)+j], j=0..7
//   B-frag:                lane l supplies B[8*(l>>4)+j][l&15]
//   D:                     col = l&15 (batch), row = 4*(l>>4)+r (gate)
// h0/h1 go through LDS [b][h] fp16, XOR-swizzled (byte ^= (b&7)<<4).

#define TT  128
#define DIN 32
#define HH  64
#define BT  16

typedef _Float16 h8 __attribute__((ext_vector_type(8)));
typedef _Float16 h4 __attribute__((ext_vector_type(4)));
typedef float    f4 __attribute__((ext_vector_type(4)));

__device__ __forceinline__ float fsig(float x) {
    // 1/(1+exp(-x)) via exp2/rcp (single hw instrs)
    return __builtin_amdgcn_rcpf(1.f + __builtin_amdgcn_exp2f(-1.44269504f * x));
}
__device__ __forceinline__ float ftanh(float x) {
    // 2/(1+exp(-2x)) - 1 ; saturates correctly via rcp(inf)=0
    return 2.f * __builtin_amdgcn_rcpf(1.f + __builtin_amdgcn_exp2f(-2.88539008f * x)) - 1.f;
}

__device__ __forceinline__ h8 cvt8(const float* p) {
    float4 a = *(const float4*)p;
    float4 b = *(const float4*)(p + 4);
    h8 r;
    r[0] = (_Float16)a.x; r[1] = (_Float16)a.y; r[2] = (_Float16)a.z; r[3] = (_Float16)a.w;
    r[4] = (_Float16)b.x; r[5] = (_Float16)b.y; r[6] = (_Float16)b.z; r[7] = (_Float16)b.w;
    return r;
}

__global__ __launch_bounds__(256, 2)
void lstm2_fused(const float* __restrict__ x,
                 const float* __restrict__ wih0, const float* __restrict__ whh0,
                 const float* __restrict__ bih0, const float* __restrict__ bhh0,
                 const float* __restrict__ wih1, const float* __restrict__ whh1,
                 const float* __restrict__ bih1, const float* __restrict__ bhh1,
                 const float* __restrict__ fcw,  const float* __restrict__ fcb,
                 float* __restrict__ out)
{
    const int tid  = threadIdx.x;
    const int lane = tid & 63;
    const int wv   = tid >> 6;      // wave 0..3  -> h-block 16*wv
    const int bl   = lane & 15;     // batch-col within tile / A-row
    const int kg   = lane >> 4;     // k-group 0..3

    // [layer][parity][b*64+h] fp16, swizzled; 2048 B per (layer,parity)
    __shared__ alignas(16) unsigned short hb[2][2][BT * HH];
    __shared__ float wpart[4][BT];

    {   // zero LDS h-buffers (t=0 reads them as h=0 initial state)
        int* p = (int*)hb;
        #pragma unroll
        for (int i = tid; i < (int)(sizeof(hb) / 4); i += 256) p[i] = 0;
    }

    // ---- load weights into A-fragments (once) ----
    h8 W0[4][3], W1[4][4];
    f4 bias0[4], bias1[4];
    #pragma unroll
    for (int q = 0; q < 4; ++q) {
        const int g = 64 * q + 16 * wv + bl;          // A-row gate index
        W0[q][0] = cvt8(wih0 + g * 32 + 8 * kg);      // k = x dims 0..31
        W0[q][1] = cvt8(whh0 + g * 64 + 8 * kg);      // k = h0 0..31
        W0[q][2] = cvt8(whh0 + g * 64 + 32 + 8 * kg); // k = h0 32..63
        W1[q][0] = cvt8(wih1 + g * 64 + 8 * kg);      // k = h0 0..31
        W1[q][1] = cvt8(wih1 + g * 64 + 32 + 8 * kg);
        W1[q][2] = cvt8(whh1 + g * 64 + 8 * kg);      // k = h1 0..31
        W1[q][3] = cvt8(whh1 + g * 64 + 32 + 8 * kg);
        const int gb = 64 * q + 16 * wv + 4 * kg;     // D-row gate index
        float4 a0 = *(const float4*)(bih0 + gb);
        float4 c0b = *(const float4*)(bhh0 + gb);
        bias0[q][0] = a0.x + c0b.x; bias0[q][1] = a0.y + c0b.y;
        bias0[q][2] = a0.z + c0b.z; bias0[q][3] = a0.w + c0b.w;
        float4 a1 = *(const float4*)(bih1 + gb);
        float4 c1b = *(const float4*)(bhh1 + gb);
        bias1[q][0] = a1.x + c1b.x; bias1[q][1] = a1.y + c1b.y;
        bias1[q][2] = a1.z + c1b.z; bias1[q][3] = a1.w + c1b.w;
    }

    const int bbase = blockIdx.x * BT;
    const float* xp = x + (size_t)(bbase + bl) * (TT * DIN) + 8 * kg;

    f4 c0 = {0.f, 0.f, 0.f, 0.f};
    f4 c1 = {0.f, 0.f, 0.f, 0.f};
    f4 h1v = {0.f, 0.f, 0.f, 0.f};

    __syncthreads();   // LDS zero visible

    h8 xcur = cvt8(xp);           // t = 0 x-fragment
    const int swz = (bl & 7) << 4;
    char* lbase = (char*)hb;
    const int rowoff = bl * 128;
    const int wroff  = rowoff + (((32 * wv + 8 * kg)) ^ swz); // write: 4 h's at h=16wv+4kg
    const int rd0    = rowoff + ((16 * kg) ^ swz);            // read halfsel 0 (h 0..31)
    const int rd1    = rowoff + ((64 + 16 * kg) ^ swz);       // read halfsel 1 (h 32..63)

    for (int t = 0; t < TT; ++t) {
        // prefetch x for t+1 (consumed at end of body)
        const int tn = (t + 1 < TT) ? t + 1 : t;
        float4 xnA = *(const float4*)(xp + tn * DIN);
        float4 xnB = *(const float4*)(xp + tn * DIN + 4);

        const int wp = t & 1, rp = wp ^ 1;

        // ---------------- layer 0 ----------------
        h8 hr0 = *(const h8*)(lbase + rp * 2048 + rd0);
        h8 hr1 = *(const h8*)(lbase + rp * 2048 + rd1);
        f4 acc0[4];
        #pragma unroll
        for (int q = 0; q < 4; ++q) {
            acc0[q] = bias0[q];
            acc0[q] = __builtin_amdgcn_mfma_f32_16x16x32_f16(W0[q][0], xcur, acc0[q], 0, 0, 0);
            acc0[q] = __builtin_amdgcn_mfma_f32_16x16x32_f16(W0[q][1], hr0,  acc0[q], 0, 0, 0);
            acc0[q] = __builtin_amdgcn_mfma_f32_16x16x32_f16(W0[q][2], hr1,  acc0[q], 0, 0, 0);
        }
        h4 hw;
        #pragma unroll
        for (int r = 0; r < 4; ++r) {
            float gi = fsig(acc0[0][r]);
            float gf = fsig(acc0[1][r]);
            float gg = ftanh(acc0[2][r]);
            float go = fsig(acc0[3][r]);
            float c  = gf * c0[r] + gi * gg;
            c0[r] = c;
            hw[r] = (_Float16)(go * ftanh(c));
        }
        *(h4*)(lbase + wp * 2048 + wroff) = hw;
        __syncthreads();

        // ---------------- layer 1 ----------------
        h8 g0a = *(const h8*)(lbase + wp * 2048 + rd0);          // h0[t] (just written)
        h8 g0b = *(const h8*)(lbase + wp * 2048 + rd1);
        h8 g1a = *(const h8*)(lbase + 4096 + rp * 2048 + rd0);   // h1[t-1]
        h8 g1b = *(const h8*)(lbase + 4096 + rp * 2048 + rd1);
        f4 acc1[4];
        #pragma unroll
        for (int q = 0; q < 4; ++q) {
            acc1[q] = bias1[q];
            acc1[q] = __builtin_amdgcn_mfma_f32_16x16x32_f16(W1[q][0], g0a, acc1[q], 0, 0, 0);
            acc1[q] = __builtin_amdgcn_mfma_f32_16x16x32_f16(W1[q][1], g0b, acc1[q], 0, 0, 0);
            acc1[q] = __builtin_amdgcn_mfma_f32_16x16x32_f16(W1[q][2], g1a, acc1[q], 0, 0, 0);
            acc1[q] = __builtin_amdgcn_mfma_f32_16x16x32_f16(W1[q][3], g1b, acc1[q], 0, 0, 0);
        }
        #pragma unroll
        for (int r = 0; r < 4; ++r) {
            float gi = fsig(acc1[0][r]);
            float gf = fsig(acc1[1][r]);
            float gg = ftanh(acc1[2][r]);
            float go = fsig(acc1[3][r]);
            float c  = gf * c1[r] + gi * gg;
            c1[r] = c;
            float h = go * ftanh(c);
            h1v[r] = h;                    // keep fp32 for the final head
            hw[r]  = (_Float16)h;
        }
        *(h4*)(lbase + 4096 + wp * 2048 + wroff) = hw;

        // convert prefetched x -> fragment for next step
        xcur[0] = (_Float16)xnA.x; xcur[1] = (_Float16)xnA.y;
        xcur[2] = (_Float16)xnA.z; xcur[3] = (_Float16)xnA.w;
        xcur[4] = (_Float16)xnB.x; xcur[5] = (_Float16)xnB.y;
        xcur[6] = (_Float16)xnB.z; xcur[7] = (_Float16)xnB.w;
        __syncthreads();
    }

    // ---- head: out[b] = h1 . fc_w + fc_b ----
    float4 fw = *(const float4*)(fcw + 16 * wv + 4 * kg);
    float part = h1v[0] * fw.x + h1v[1] * fw.y + h1v[2] * fw.z + h1v[3] * fw.w;
    part += __shfl_xor(part, 16, 64);
    part += __shfl_xor(part, 32, 64);
    if (lane < 16) wpart[wv][lane] = part;
    __syncthreads();
    if (tid < BT)
        out[bbase + tid] = wpart[0][tid] + wpart[1][tid] + wpart[2][tid] + wpart[3][tid] + fcb[0];
}

extern "C" void kernel_launch(void* const* d_in, const int* in_sizes, int n_in,
                              void* d_out, int out_size, void* d_ws, size_t ws_size,
                              hipStream_t stream) {
    (void)in_sizes; (void)n_in; (void)d_ws; (void)ws_size; (void)out_size;
    lstm2_fused<<<dim3(8192 / BT), dim3(256), 0, stream>>>(
        (const float*)d_in[0],
        (const float*)d_in[1], (const float*)d_in[2],
        (const float*)d_in[3], (const float*)d_in[4],
        (const float*)d_in[5], (const float*)d_in[6],
        (const float*)d_in[7], (const float*)d_in[8],
        (const float*)d_in[9], (const float*)d_in[10],
        (float*)d_out);
}

// Round 3
// 227.218 us; speedup vs baseline: 1.0878x; 1.0878x over previous
//
#include <hip/hip_runtime.h>

// 2-layer fused LSTM + linear head.  B=8192, T=128, D=32, H=64, gates=256.
// Per WG (256 thr = 4 waves): BT=16 batch rows, all 128 steps, both layers.
// R2: layer-1 skewed by one timestep -> ONE barrier per iteration, and
// L0[t] / L1[t-1] are independent (share the h0[t-1] LDS read).
//   A-frag (16x16x32 f16): lane l supplies A[l&15][8*(l>>4)+j]
//   B-frag:                lane l supplies B[8*(l>>4)+j][l&15]
//   D:                     col = l&15 (batch), row = 4*(l>>4)+r (gate)

#define TT  128
#define DIN 32
#define HH  64
#define BT  16

typedef _Float16 h8 __attribute__((ext_vector_type(8)));
typedef _Float16 h4 __attribute__((ext_vector_type(4)));
typedef __fp16   p2 __attribute__((ext_vector_type(2)));   // cvt_pkrtz result type
typedef float    f4 __attribute__((ext_vector_type(4)));

__device__ __forceinline__ float fsig(float x) {
    return __builtin_amdgcn_rcpf(1.f + __builtin_amdgcn_exp2f(-1.44269504f * x));
}
__device__ __forceinline__ float ftanh(float x) {
    return 2.f * __builtin_amdgcn_rcpf(1.f + __builtin_amdgcn_exp2f(-2.88539008f * x)) - 1.f;
}

__device__ __forceinline__ h8 cvt8(const float* p) {
    float4 a = *(const float4*)p;
    float4 b = *(const float4*)(p + 4);
    union { h8 v; p2 p[4]; } u;
    u.p[0] = __builtin_amdgcn_cvt_pkrtz(a.x, a.y);
    u.p[1] = __builtin_amdgcn_cvt_pkrtz(a.z, a.w);
    u.p[2] = __builtin_amdgcn_cvt_pkrtz(b.x, b.y);
    u.p[3] = __builtin_amdgcn_cvt_pkrtz(b.z, b.w);
    return u.v;
}

__global__ __launch_bounds__(256, 2)
void lstm2_fused(const float* __restrict__ x,
                 const float* __restrict__ wih0, const float* __restrict__ whh0,
                 const float* __restrict__ bih0, const float* __restrict__ bhh0,
                 const float* __restrict__ wih1, const float* __restrict__ whh1,
                 const float* __restrict__ bih1, const float* __restrict__ bhh1,
                 const float* __restrict__ fcw,  const float* __restrict__ fcb,
                 float* __restrict__ out)
{
    const int tid  = threadIdx.x;
    const int lane = tid & 63;
    const int wv   = tid >> 6;
    const int bl   = lane & 15;
    const int kg   = lane >> 4;

    // [layer][parity][b*64+h] fp16, XOR-swizzled; 2048 B per (layer,parity)
    __shared__ alignas(16) unsigned short hb[2][2][BT * HH];
    __shared__ float wpart[4][BT];

    {
        int* p = (int*)hb;
        for (int i = tid; i < (int)(sizeof(hb) / 4); i += 256) p[i] = 0;
    }

    // ---- weights as A-fragments (resident for whole kernel) ----
    h8 W0[4][3], W1[4][4];
    f4 bias0[4], bias1[4];
    #pragma unroll
    for (int q = 0; q < 4; ++q) {
        const int g = 64 * q + 16 * wv + bl;
        W0[q][0] = cvt8(wih0 + g * 32 + 8 * kg);
        W0[q][1] = cvt8(whh0 + g * 64 + 8 * kg);
        W0[q][2] = cvt8(whh0 + g * 64 + 32 + 8 * kg);
        W1[q][0] = cvt8(wih1 + g * 64 + 8 * kg);
        W1[q][1] = cvt8(wih1 + g * 64 + 32 + 8 * kg);
        W1[q][2] = cvt8(whh1 + g * 64 + 8 * kg);
        W1[q][3] = cvt8(whh1 + g * 64 + 32 + 8 * kg);
        const int gb = 64 * q + 16 * wv + 4 * kg;
        float4 a0 = *(const float4*)(bih0 + gb);
        float4 c0b = *(const float4*)(bhh0 + gb);
        bias0[q][0] = a0.x + c0b.x; bias0[q][1] = a0.y + c0b.y;
        bias0[q][2] = a0.z + c0b.z; bias0[q][3] = a0.w + c0b.w;
        float4 a1 = *(const float4*)(bih1 + gb);
        float4 c1b = *(const float4*)(bhh1 + gb);
        bias1[q][0] = a1.x + c1b.x; bias1[q][1] = a1.y + c1b.y;
        bias1[q][2] = a1.z + c1b.z; bias1[q][3] = a1.w + c1b.w;
    }

    const int bbase = blockIdx.x * BT;
    const float* xp = x + (size_t)(bbase + bl) * (TT * DIN) + 8 * kg;

    f4 c0 = {0.f, 0.f, 0.f, 0.f};
    f4 c1 = {0.f, 0.f, 0.f, 0.f};
    f4 h1v = {0.f, 0.f, 0.f, 0.f};

    __syncthreads();   // LDS zero visible

    h8 xcur = cvt8(xp);   // x[0]
    const int swz = (bl & 7) << 4;
    char* lbase = (char*)hb;
    const int rowoff = bl * 128;
    const int wroff  = rowoff + ((32 * wv + 8 * kg) ^ swz);
    const int rd0    = rowoff + ((16 * kg) ^ swz);
    const int rd1    = rowoff + ((64 + 16 * kg) ^ swz);

    // L0 body: consumes xcur + h0[prev] (hr0,hr1), writes h0[wp]
    auto L0 = [&](const h8& hr0, const h8& hr1, int wp) {
        f4 acc0[4];
        #pragma unroll
        for (int q = 0; q < 4; ++q) {
            acc0[q] = bias0[q];
            acc0[q] = __builtin_amdgcn_mfma_f32_16x16x32_f16(W0[q][0], xcur, acc0[q], 0, 0, 0);
            acc0[q] = __builtin_amdgcn_mfma_f32_16x16x32_f16(W0[q][1], hr0,  acc0[q], 0, 0, 0);
            acc0[q] = __builtin_amdgcn_mfma_f32_16x16x32_f16(W0[q][2], hr1,  acc0[q], 0, 0, 0);
        }
        union { h4 v; p2 p[2]; } u;
        float hv[4];
        #pragma unroll
        for (int r = 0; r < 4; ++r) {
            float gi = fsig(acc0[0][r]);
            float gf = fsig(acc0[1][r]);
            float gg = ftanh(acc0[2][r]);
            float go = fsig(acc0[3][r]);
            float c  = gf * c0[r] + gi * gg;
            c0[r] = c;
            hv[r] = go * ftanh(c);
        }
        u.p[0] = __builtin_amdgcn_cvt_pkrtz(hv[0], hv[1]);
        u.p[1] = __builtin_amdgcn_cvt_pkrtz(hv[2], hv[3]);
        *(h4*)(lbase + wp * 2048 + wroff) = u.v;
    };

    // L1 body: consumes h0[t'] (hr0,hr1) + h1[t'-1] (g1a,g1b), writes h1[wp]
    auto L1 = [&](const h8& hr0, const h8& hr1, const h8& g1a, const h8& g1b,
                  int wp, bool store) {
        f4 acc1[4];
        #pragma unroll
        for (int q = 0; q < 4; ++q) {
            acc1[q] = bias1[q];
            acc1[q] = __builtin_amdgcn_mfma_f32_16x16x32_f16(W1[q][0], hr0, acc1[q], 0, 0, 0);
            acc1[q] = __builtin_amdgcn_mfma_f32_16x16x32_f16(W1[q][1], hr1, acc1[q], 0, 0, 0);
            acc1[q] = __builtin_amdgcn_mfma_f32_16x16x32_f16(W1[q][2], g1a, acc1[q], 0, 0, 0);
            acc1[q] = __builtin_amdgcn_mfma_f32_16x16x32_f16(W1[q][3], g1b, acc1[q], 0, 0, 0);
        }
        union { h4 v; p2 p[2]; } u;
        #pragma unroll
        for (int r = 0; r < 4; ++r) {
            float gi = fsig(acc1[0][r]);
            float gf = fsig(acc1[1][r]);
            float gg = ftanh(acc1[2][r]);
            float go = fsig(acc1[3][r]);
            float c  = gf * c1[r] + gi * gg;
            c1[r] = c;
            h1v[r] = go * ftanh(c);
        }
        u.p[0] = __builtin_amdgcn_cvt_pkrtz(h1v[0], h1v[1]);
        u.p[1] = __builtin_amdgcn_cvt_pkrtz(h1v[2], h1v[3]);
        if (store) *(h4*)(lbase + 4096 + wp * 2048 + wroff) = u.v;
    };

    // ---- it = 0: L0 only (t=0), reads zeroed h0 buf1 ----
    {
        float4 xnA = *(const float4*)(xp + 1 * DIN);
        float4 xnB = *(const float4*)(xp + 1 * DIN + 4);
        h8 hr0 = *(const h8*)(lbase + 1 * 2048 + rd0);
        h8 hr1 = *(const h8*)(lbase + 1 * 2048 + rd1);
        L0(hr0, hr1, 0);
        union { h8 v; p2 p[4]; } u;
        u.p[0] = __builtin_amdgcn_cvt_pkrtz(xnA.x, xnA.y);
        u.p[1] = __builtin_amdgcn_cvt_pkrtz(xnA.z, xnA.w);
        u.p[2] = __builtin_amdgcn_cvt_pkrtz(xnB.x, xnB.y);
        u.p[3] = __builtin_amdgcn_cvt_pkrtz(xnB.z, xnB.w);
        xcur = u.v;
        __syncthreads();
    }

    // ---- it = 1..TT-1: L0(t=it) + L1(t=it-1), one barrier ----
    for (int it = 1; it < TT; ++it) {
        const int wp = it & 1, rp = wp ^ 1;
        const int tn = (it + 1 < TT) ? it + 1 : TT - 1;
        float4 xnA = *(const float4*)(xp + tn * DIN);
        float4 xnB = *(const float4*)(xp + tn * DIN + 4);

        h8 hr0 = *(const h8*)(lbase + rp * 2048 + rd0);          // h0[it-1]
        h8 hr1 = *(const h8*)(lbase + rp * 2048 + rd1);
        h8 g1a = *(const h8*)(lbase + 4096 + rp * 2048 + rd0);   // h1[it-2]
        h8 g1b = *(const h8*)(lbase + 4096 + rp * 2048 + rd1);

        L0(hr0, hr1, wp);
        L1(hr0, hr1, g1a, g1b, wp, true);

        union { h8 v; p2 p[4]; } u;
        u.p[0] = __builtin_amdgcn_cvt_pkrtz(xnA.x, xnA.y);
        u.p[1] = __builtin_amdgcn_cvt_pkrtz(xnA.z, xnA.w);
        u.p[2] = __builtin_amdgcn_cvt_pkrtz(xnB.x, xnB.y);
        u.p[3] = __builtin_amdgcn_cvt_pkrtz(xnB.z, xnB.w);
        xcur = u.v;
        __syncthreads();
    }

    // ---- it = TT: L1 only (t=TT-1) ----
    {
        const int rp = (TT & 1) ^ 1;   // = 1
        h8 hr0 = *(const h8*)(lbase + rp * 2048 + rd0);          // h0[TT-1]
        h8 hr1 = *(const h8*)(lbase + rp * 2048 + rd1);
        h8 g1a = *(const h8*)(lbase + 4096 + rp * 2048 + rd0);   // h1[TT-2]
        h8 g1b = *(const h8*)(lbase + 4096 + rp * 2048 + rd1);
        L1(hr0, hr1, g1a, g1b, 0, false);
    }

    // ---- head: out[b] = h1 . fc_w + fc_b ----
    float4 fw = *(const float4*)(fcw + 16 * wv + 4 * kg);
    float part = h1v[0] * fw.x + h1v[1] * fw.y + h1v[2] * fw.z + h1v[3] * fw.w;
    part += __shfl_xor(part, 16, 64);
    part += __shfl_xor(part, 32, 64);
    if (lane < 16) wpart[wv][lane] = part;
    __syncthreads();
    if (tid < BT)
        out[bbase + tid] = wpart[0][tid] + wpart[1][tid] + wpart[2][tid] + wpart[3][tid] + fcb[0];
}

extern "C" void kernel_launch(void* const* d_in, const int* in_sizes, int n_in,
                              void* d_out, int out_size, void* d_ws, size_t ws_size,
                              hipStream_t stream) {
    (void)in_sizes; (void)n_in; (void)d_ws; (void)ws_size; (void)out_size;
    lstm2_fused<<<dim3(8192 / BT), dim3(256), 0, stream>>>(
        (const float*)d_in[0],
        (const float*)d_in[1], (const float*)d_in[2],
        (const float*)d_in[3], (const float*)d_in[4],
        (const float*)d_in[5], (const float*)d_in[6],
        (const float*)d_in[7], (const float*)d_in[8],
        (const float*)d_in[9], (const float*)d_in[10],
        (float*)d_out);
}

// Round 4
// 184.804 us; speedup vs baseline: 1.3374x; 1.2295x over previous
//
#include <hip/hip_runtime.h>

// 2-layer fused LSTM + linear head.  B=8192, T=128, D=32, H=64, gates=256.
// R4: 8 waves/block (512 thr), BT=16, grid 512 -> 4 waves/SIMD.
// Wave wv owns h in [8wv, 8wv+8) as 2 row-tiles with GATE-INTERLEAVED rows:
//   tile row rho <-> weight row gate(rho&3), h = hbase + (rho>>2)
//   => D element r of lane (bl,kg) = gate r of h = hbase+kg  (all 4 gates/lane)
// log2e folded into weights (i,f,o x1.4427; g x2.8854); merged-rcp gate math:
//   7 trans/element instead of 10.

#define TT  128
#define DIN 32
#define BT  16
#define L2E 1.44269504088896340736f

typedef _Float16 h8 __attribute__((ext_vector_type(8)));
typedef __fp16   p2 __attribute__((ext_vector_type(2)));
typedef float    f4 __attribute__((ext_vector_type(4)));

__device__ __forceinline__ h8 cvt8s(const float* p, float s) {
    float4 a = *(const float4*)p;
    float4 b = *(const float4*)(p + 4);
    union { h8 v; p2 q[4]; } u;
    u.q[0] = __builtin_amdgcn_cvt_pkrtz(a.x * s, a.y * s);
    u.q[1] = __builtin_amdgcn_cvt_pkrtz(a.z * s, a.w * s);
    u.q[2] = __builtin_amdgcn_cvt_pkrtz(b.x * s, b.y * s);
    u.q[3] = __builtin_amdgcn_cvt_pkrtz(b.z * s, b.w * s);
    return u.v;
}
__device__ __forceinline__ h8 cvt8(const float* p) {
    float4 a = *(const float4*)p;
    float4 b = *(const float4*)(p + 4);
    union { h8 v; p2 q[4]; } u;
    u.q[0] = __builtin_amdgcn_cvt_pkrtz(a.x, a.y);
    u.q[1] = __builtin_amdgcn_cvt_pkrtz(a.z, a.w);
    u.q[2] = __builtin_amdgcn_cvt_pkrtz(b.x, b.y);
    u.q[3] = __builtin_amdgcn_cvt_pkrtz(b.z, b.w);
    return u.v;
}

// acc = {yi', yf', yg'(2x-scaled), yo'}; returns h, updates c.  7 trans ops.
__device__ __forceinline__ float elem(const f4& acc, float& c) {
    float Ei = __builtin_amdgcn_exp2f(-acc[0]);
    float Ef = __builtin_amdgcn_exp2f(-acc[1]);
    float Eg = __builtin_amdgcn_exp2f(-acc[2]);
    float Eo = __builtin_amdgcn_exp2f(-acc[3]);
    float a = 1.f + Ei, b = 1.f + Eg, d = 1.f + Ef;
    float P = a * b;
    float N = c * P + (1.f - Eg) * d;
    c = N * __builtin_amdgcn_rcpf(P * d);
    float Ec = __builtin_amdgcn_exp2f(-2.f * L2E * c);
    return (1.f - Ec) * __builtin_amdgcn_rcpf((1.f + Ec) * (1.f + Eo));
}

__global__ __launch_bounds__(512, 4)
void lstm2_fused(const float* __restrict__ x,
                 const float* __restrict__ wih0, const float* __restrict__ whh0,
                 const float* __restrict__ bih0, const float* __restrict__ bhh0,
                 const float* __restrict__ wih1, const float* __restrict__ whh1,
                 const float* __restrict__ bih1, const float* __restrict__ bhh1,
                 const float* __restrict__ fcw,  const float* __restrict__ fcb,
                 float* __restrict__ out)
{
    const int tid  = threadIdx.x;
    const int lane = tid & 63;
    const int wv   = tid >> 6;      // 0..7 -> h block 8*wv
    const int bl   = lane & 15;
    const int kg   = lane >> 4;

    __shared__ alignas(16) unsigned short hb[2][2][BT * 64];  // layer,parity,[b][h] f16
    __shared__ float wpart[8][BT];

    for (int i = tid; i < (int)(sizeof(hb) / 4); i += 512) ((int*)hb)[i] = 0;

    // ---- weights: gate-interleaved row tiles, log2e folded ----
    h8 W0[2][3], W1[2][4];
    f4 b0v[2], b1v[2];
    #pragma unroll
    for (int t = 0; t < 2; ++t) {
        const int hbse = 8 * wv + 4 * t;
        const int gam  = bl & 3;                         // gate of this A-row
        const int g    = 64 * gam + hbse + (bl >> 2);    // global weight row
        const float sc = (gam == 2) ? 2.f * L2E : L2E;
        W0[t][0] = cvt8s(wih0 + g * 32 + 8 * kg, sc);
        W0[t][1] = cvt8s(whh0 + g * 64 + 8 * kg, sc);
        W0[t][2] = cvt8s(whh0 + g * 64 + 32 + 8 * kg, sc);
        W1[t][0] = cvt8s(wih1 + g * 64 + 8 * kg, sc);
        W1[t][1] = cvt8s(wih1 + g * 64 + 32 + 8 * kg, sc);
        W1[t][2] = cvt8s(whh1 + g * 64 + 8 * kg, sc);
        W1[t][3] = cvt8s(whh1 + g * 64 + 32 + 8 * kg, sc);
        #pragma unroll
        for (int r = 0; r < 4; ++r) {
            const int gr = 64 * r + hbse + kg;           // D element r = gate r of h=hbse+kg
            const float scr = (r == 2) ? 2.f * L2E : L2E;
            b0v[t][r] = (bih0[gr] + bhh0[gr]) * scr;
            b1v[t][r] = (bih1[gr] + bhh1[gr]) * scr;
        }
    }

    const int bbase = blockIdx.x * BT;
    const float* xp = x + (size_t)(bbase + bl) * (TT * DIN) + 8 * kg;

    float c0[2] = {0.f, 0.f}, c1[2] = {0.f, 0.f}, h1f[2] = {0.f, 0.f};

    __syncthreads();   // LDS zero visible

    const int swz = (bl & 7) << 4;
    char* lb = (char*)hb;
    const int rowoff = bl * 128;
    const int rd0 = rowoff + ((16 * kg) ^ swz);
    const int rd1 = rowoff + ((64 + 16 * kg) ^ swz);
    const int wro0 = rowoff + ((16 * wv + 2 * kg) ^ swz);        // h = 8wv+kg   (t=0)
    const int wro1 = rowoff + ((16 * wv + 8 + 2 * kg) ^ swz);    // h = 8wv+4+kg (t=1)

    auto L0 = [&](const h8& xc, const h8& hr0, const h8& hr1, int wp) {
        #pragma unroll
        for (int t = 0; t < 2; ++t) {
            f4 acc = b0v[t];
            acc = __builtin_amdgcn_mfma_f32_16x16x32_f16(W0[t][1], hr0, acc, 0, 0, 0);
            acc = __builtin_amdgcn_mfma_f32_16x16x32_f16(W0[t][2], hr1, acc, 0, 0, 0);
            acc = __builtin_amdgcn_mfma_f32_16x16x32_f16(W0[t][0], xc,  acc, 0, 0, 0);
            float h = elem(acc, c0[t]);
            *(_Float16*)(lb + wp * 2048 + (t ? wro1 : wro0)) = (_Float16)h;
        }
    };

    auto L1 = [&](const h8& g0a, const h8& g0b, const h8& g1a, const h8& g1b,
                  int wp, bool store) {
        #pragma unroll
        for (int t = 0; t < 2; ++t) {
            f4 acc = b1v[t];
            acc = __builtin_amdgcn_mfma_f32_16x16x32_f16(W1[t][0], g0a, acc, 0, 0, 0);
            acc = __builtin_amdgcn_mfma_f32_16x16x32_f16(W1[t][1], g0b, acc, 0, 0, 0);
            acc = __builtin_amdgcn_mfma_f32_16x16x32_f16(W1[t][2], g1a, acc, 0, 0, 0);
            acc = __builtin_amdgcn_mfma_f32_16x16x32_f16(W1[t][3], g1b, acc, 0, 0, 0);
            float h = elem(acc, c1[t]);
            h1f[t] = h;
            if (store) *(_Float16*)(lb + 4096 + wp * 2048 + (t ? wro1 : wro0)) = (_Float16)h;
        }
    };

    // ---- it = 0: L0 only (t=0); h0[-1]=0 from zeroed parity-1 buffer ----
    {
        h8 xc  = cvt8(xp);
        h8 hr0 = *(const h8*)(lb + 2048 + rd0);
        h8 hr1 = *(const h8*)(lb + 2048 + rd1);
        L0(xc, hr0, hr1, 0);
        __syncthreads();
    }

    // ---- it = 1..TT-1: L0(t=it) + L1(t=it-1), one barrier ----
    for (int it = 1; it < TT; ++it) {
        const int wp = it & 1, rp = wp ^ 1;
        h8 xc  = cvt8(xp + it * DIN);
        h8 hr0 = *(const h8*)(lb + rp * 2048 + rd0);          // h0[it-1]
        h8 hr1 = *(const h8*)(lb + rp * 2048 + rd1);
        h8 g1a = *(const h8*)(lb + 4096 + rp * 2048 + rd0);   // h1[it-2]
        h8 g1b = *(const h8*)(lb + 4096 + rp * 2048 + rd1);
        L0(xc, hr0, hr1, wp);
        L1(hr0, hr1, g1a, g1b, wp, true);
        __syncthreads();
    }

    // ---- tail: L1 for t = TT-1 ----
    {
        const int rp = 1;   // TT even: last write parity
        h8 hr0 = *(const h8*)(lb + rp * 2048 + rd0);          // h0[TT-1]
        h8 hr1 = *(const h8*)(lb + rp * 2048 + rd1);
        h8 g1a = *(const h8*)(lb + 4096 + rp * 2048 + rd0);   // h1[TT-2]
        h8 g1b = *(const h8*)(lb + 4096 + rp * 2048 + rd1);
        L1(hr0, hr1, g1a, g1b, 0, false);
    }

    // ---- head: out[b] = h1 . fc_w + fc_b ----
    float part = h1f[0] * fcw[8 * wv + kg] + h1f[1] * fcw[8 * wv + 4 + kg];
    part += __shfl_xor(part, 16, 64);
    part += __shfl_xor(part, 32, 64);
    if (lane < 16) wpart[wv][lane] = part;
    __syncthreads();
    if (tid < BT) {
        float s = fcb[0];
        #pragma unroll
        for (int w = 0; w < 8; ++w) s += wpart[w][tid];
        out[bbase + tid] = s;
    }
}

extern "C" void kernel_launch(void* const* d_in, const int* in_sizes, int n_in,
                              void* d_out, int out_size, void* d_ws, size_t ws_size,
                              hipStream_t stream) {
    (void)in_sizes; (void)n_in; (void)d_ws; (void)ws_size; (void)out_size;
    lstm2_fused<<<dim3(8192 / BT), dim3(512), 0, stream>>>(
        (const float*)d_in[0],
        (const float*)d_in[1], (const float*)d_in[2],
        (const float*)d_in[3], (const float*)d_in[4],
        (const float*)d_in[5], (const float*)d_in[6],
        (const float*)d_in[7], (const float*)d_in[8],
        (const float*)d_in[9], (const float*)d_in[10],
        (float*)d_out);
}